// Round 7
// baseline (243.818 us; speedup 1.0000x reference)
//
#include <hip/hip_runtime.h>

// GroupNorm(32) -> phi 1x1 -> soft-VQ softmax vs codebook -> wz 1x1 + residual. fp32 I/O.
// x:(10,64,128,128), mb:(64,512), phi_w/wz_w:(64,64). B=10, C=64, HW=16384, K=512.
//
// One wave = 64 tokens (4 MFMA N-groups sharing all A-frag loads).
// All stages transposed (M=feature, N=token): C col = lane&15 = token everywhere.
// Per-wave LDS: ONE 64x72-ushort buffer (R6's double buffer bought nothing and
// halved occupancy). Stride 72 = 36 dwords = 4 mod 32 -> b64 writes / b128 reads
// are bank-floor-optimal (measured: SQ_LDS_BANK_CONFLICT == structural width cost
// exactly; zero true conflicts). No __syncthreads: all LDS deps intra-wave.
// VALU diet: P is pre-scaled by 0.125*log2(e) so softmax exp is a bare v_exp_f32
// (exp2f); bf16 pair-packing via one v_perm_b32.
//
// ws (ushort):
//  [0    ..32768) mbA  scores A-frags  (((cc*4+u)*2+s)*64+lane)*8+j = mb[s*32+q*8+j][(cc*4+u)*16+m]
//  [32768..65536) mbY  Y A-frags       (((cc*2+s2)*4+mt)*64+lane)*8+j = mb[mt*16+m][cc*64+s2*32+q*8+j]
//  [65536..69632) phiA ((mt*2+s)*64+lane)*8+j = phi_w[mt*16+m][s*32+q*8+j]
//  [69632..73728) wzA  same for wz_w
//  float view at ushort 73728 (= statf): [0..320) sum[b*32+g], [320..640) sumsq  (atomic partials)

#define HWN 16384
#define CCH 64
#define PSC 0.18033688011112042f   // 0.125 * log2(e)

using short8 = __attribute__((ext_vector_type(8))) short;
using f32x4  = __attribute__((ext_vector_type(4))) float;

__device__ __forceinline__ ushort f2bf(float f) {
    union { float f; unsigned int i; } v; v.f = f;
    return (ushort)((v.i + 0x8000u) >> 16);   // round-half-up
}
__device__ __forceinline__ unsigned int pk2(float a, float b) {
    union { float f; unsigned int i; } va, vb; va.f = a; vb.f = b;
    // hi16(a+0x8000) -> low half, hi16(b+0x8000) -> high half: one v_perm_b32
    return __builtin_amdgcn_perm(vb.i + 0x8000u, va.i + 0x8000u, 0x07060302u);
}

// blocks [0, nstat): GroupNorm partial sums (4 blocks per (b,g), atomicAdd into statf).
// blocks [nstat, nstat+288): weight prep gathers.
__global__ __launch_bounds__(256) void prep_stats_kernel(
    const float* __restrict__ x, const float* __restrict__ mb,
    const float* __restrict__ phiw, const float* __restrict__ wzw,
    ushort* __restrict__ ws, int nstat)
{
    if (blockIdx.x >= nstat) {
        int i = (blockIdx.x - nstat) * 256 + threadIdx.x;   // 0..73727
        int j = i & 7, lane = (i >> 3) & 63, m = lane & 15, q = lane >> 4;
        if (i < 32768) {
            int t = i >> 9, tile = t >> 1, s = t & 1;
            ws[i] = f2bf(mb[(s * 32 + q * 8 + j) * 512 + tile * 16 + m]);
        } else if (i < 65536) {
            int t = (i - 32768) >> 9;
            int mt = t & 3, u2 = t >> 2, s2 = u2 & 1, cc = u2 >> 1;
            ws[i] = f2bf(mb[(mt * 16 + m) * 512 + cc * 64 + s2 * 32 + q * 8 + j]);
        } else if (i < 69632) {
            int t = (i - 65536) >> 9, mt = t >> 1, s = t & 1;
            ws[i] = f2bf(phiw[(mt * 16 + m) * 64 + s * 32 + q * 8 + j]);
        } else {
            int t = (i - 69632) >> 9, mt = t >> 1, s = t & 1;
            ws[i] = f2bf(wzw[(mt * 16 + m) * 64 + s * 32 + q * 8 + j]);
        }
        return;
    }
    float* statf = (float*)(ws + 73728);
    int blk  = blockIdx.x;            // b*128 + g*4 + part
    int b    = blk >> 7;
    int g    = (blk >> 2) & 31;
    int part = blk & 3;
    const float4* b4 = (const float4*)(x + (size_t)b * CCH * HWN + (size_t)(g * 2) * HWN) + part * 2048;
    float s = 0.f, s2 = 0.f;
    for (int i = threadIdx.x; i < 2048; i += 256) {
        float4 u = b4[i];
        s  += (u.x + u.y) + (u.z + u.w);
        s2 += (u.x*u.x + u.y*u.y) + (u.z*u.z + u.w*u.w);
    }
    for (int off = 32; off > 0; off >>= 1) {
        s  += __shfl_down(s, off);
        s2 += __shfl_down(s2, off);
    }
    __shared__ float rs[4], rs2[4];
    int wave = threadIdx.x >> 6, lane = threadIdx.x & 63;
    if (lane == 0) { rs[wave] = s; rs2[wave] = s2; }
    __syncthreads();
    if (threadIdx.x == 0) {
        atomicAdd(&statf[b * 32 + g],       rs[0] + rs[1] + rs[2] + rs[3]);
        atomicAdd(&statf[320 + b * 32 + g], rs2[0] + rs2[1] + rs2[2] + rs2[3]);
    }
}

__global__ __launch_bounds__(128, 4) void main_mfma(
    const float* __restrict__ x, const ushort* __restrict__ ws,
    const float* __restrict__ phib, const float* __restrict__ gnw,
    const float* __restrict__ gnb, const float* __restrict__ wzb,
    float* __restrict__ out)
{
    const int lane = threadIdx.x & 63, wv = threadIdx.x >> 6;
    const int m = lane & 15, q = lane >> 4;
    const int blk = blockIdx.x;                       // 1280 blocks, 128 tokens each
    const int b   = blk >> 7;                         // 128 blocks per image
    const int hw0 = ((blk & 127) << 7) + (wv << 6);   // this wave's 64 tokens

    const ushort* mbA  = ws;
    const ushort* mbY  = ws + 32768;
    const ushort* phiA = ws + 65536;
    const ushort* wzA  = ws + 69632;
    const float*  statf = (const float*)(ws + 73728);

    __shared__ ushort Sl[2][64 * 72];                 // one buffer per wave
    ushort* E0 = &Sl[wv][0];

    const float* xb = x + (size_t)b * CCH * HWN;

    // ---- stage 1: x -> GroupNorm (finalize stats from atomic sums) -> bf16 B-frags ----
    short8 bx[4][2];
#pragma unroll
    for (int s = 0; s < 2; ++s) {
        const int cbase = s * 32 + q * 8;
        f32x4 sm4 = *(const f32x4*)(statf + b * 32 + (cbase >> 1));
        f32x4 sq4 = *(const f32x4*)(statf + 320 + b * 32 + (cbase >> 1));
        f32x4 mu4, rs4;
#pragma unroll
        for (int r = 0; r < 4; ++r) {
            mu4[r] = sm4[r] * (1.f / 32768.f);
            float var = sq4[r] * (1.f / 32768.f) - mu4[r] * mu4[r];
            rs4[r] = rsqrtf(var + 1e-6f);
        }
        f32x4 gwv0 = *(const f32x4*)(gnw + cbase), gwv1 = *(const f32x4*)(gnw + cbase + 4);
        f32x4 gbv0 = *(const f32x4*)(gnb + cbase), gbv1 = *(const f32x4*)(gnb + cbase + 4);
#pragma unroll
        for (int n = 0; n < 4; ++n)
#pragma unroll
        for (int j = 0; j < 8; ++j) {
            float v  = xb[(size_t)(cbase + j) * HWN + hw0 + n * 16 + m];
            float gw = (j < 4) ? gwv0[j & 3] : gwv1[j & 3];
            float gb = (j < 4) ? gbv0[j & 3] : gbv1[j & 3];
            float xn = (v - mu4[j >> 1]) * rs4[j >> 1] * gw + gb;
            bx[n][s][j] = (short)f2bf(xn);
        }
    }

    // ---- P^T = phi_w * xn ; store scaled by PSC so exp(s/8) == exp2(score) ----
#pragma unroll
    for (int mt = 0; mt < 4; ++mt) {
        f32x4 a[4];
#pragma unroll
        for (int n = 0; n < 4; ++n) a[n] = (f32x4){0.f,0.f,0.f,0.f};
#pragma unroll
        for (int s = 0; s < 2; ++s) {
            short8 ap = *(const short8*)(phiA + (((mt * 2 + s) * 64 + lane) << 3));
#pragma unroll
            for (int n = 0; n < 4; ++n)
                a[n] = __builtin_amdgcn_mfma_f32_16x16x32_bf16(ap, bx[n][s], a[n], 0, 0, 0);
        }
        f32x4 pb = *(const f32x4*)(phib + mt * 16 + q * 4);
#pragma unroll
        for (int n = 0; n < 4; ++n)
            *(uint2*)(E0 + (n * 16 + m) * 72 + mt * 16 + q * 4) =
                make_uint2(pk2((a[n][0]+pb[0])*PSC, (a[n][1]+pb[1])*PSC),
                           pk2((a[n][2]+pb[2])*PSC, (a[n][3]+pb[3])*PSC));
    }

    // hoist this lane's token-rows of P (chunk-invariant score B-frags)
    short8 bp[4][2];
#pragma unroll
    for (int n = 0; n < 4; ++n)
#pragma unroll
    for (int s = 0; s < 2; ++s)
        bp[n][s] = *(const short8*)(E0 + (n * 16 + m) * 72 + s * 32 + q * 8);

    // ---- streaming softmax + Y over 8 chunks of 64 codebook entries ----
    f32x4 accY[4][4];
#pragma unroll
    for (int n = 0; n < 4; ++n)
#pragma unroll
    for (int mt = 0; mt < 4; ++mt) accY[n][mt] = (f32x4){0.f,0.f,0.f,0.f};
    float lsum[4] = {0.f, 0.f, 0.f, 0.f};

    for (int cc = 0; cc < 8; ++cc) {
#pragma unroll
        for (int u = 0; u < 4; ++u) {
            short8 am0 = *(const short8*)(mbA + ((((cc * 4 + u) * 2 + 0) * 64 + lane) << 3));
            short8 am1 = *(const short8*)(mbA + ((((cc * 4 + u) * 2 + 1) * 64 + lane) << 3));
#pragma unroll
            for (int n = 0; n < 4; ++n) {
                f32x4 sa = {0.f,0.f,0.f,0.f};
                sa = __builtin_amdgcn_mfma_f32_16x16x32_bf16(am0, bp[n][0], sa, 0, 0, 0);
                sa = __builtin_amdgcn_mfma_f32_16x16x32_bf16(am1, bp[n][1], sa, 0, 0, 0);
                float e0 = __builtin_exp2f(sa[0]), e1 = __builtin_exp2f(sa[1]);
                float e2 = __builtin_exp2f(sa[2]), e3 = __builtin_exp2f(sa[3]);
                lsum[n] += (e0 + e1) + (e2 + e3);
                *(uint2*)(E0 + (n * 16 + m) * 72 + u * 16 + q * 4) =
                    make_uint2(pk2(e0, e1), pk2(e2, e3));
            }
        }
#pragma unroll
        for (int s2 = 0; s2 < 2; ++s2) {
            short8 be[4];
#pragma unroll
            for (int n = 0; n < 4; ++n)
                be[n] = *(const short8*)(E0 + (n * 16 + m) * 72 + s2 * 32 + q * 8);
#pragma unroll
            for (int mt = 0; mt < 4; ++mt) {
                short8 ay = *(const short8*)(mbY + ((((cc * 2 + s2) * 4 + mt) * 64 + lane) << 3));
#pragma unroll
                for (int n = 0; n < 4; ++n)
                    accY[n][mt] = __builtin_amdgcn_mfma_f32_16x16x32_bf16(ay, be[n], accY[n][mt], 0, 0, 0);
            }
        }
    }

    // softmax denominators: lane's C-column IS its token; reduce across q
    float linv[4];
#pragma unroll
    for (int n = 0; n < 4; ++n) {
        float l = lsum[n];
        l += __shfl_xor(l, 16);
        l += __shfl_xor(l, 32);
        linv[n] = 1.f / l;
    }

    // ---- Y -> LDS (B-layout), then Out^T = wz * Y ----
#pragma unroll
    for (int mt = 0; mt < 4; ++mt)
#pragma unroll
    for (int n = 0; n < 4; ++n)
        *(uint2*)(E0 + (n * 16 + m) * 72 + mt * 16 + q * 4) =
            make_uint2(pk2(accY[n][mt][0], accY[n][mt][1]), pk2(accY[n][mt][2], accY[n][mt][3]));

    short8 by[4][2];
#pragma unroll
    for (int n = 0; n < 4; ++n)
#pragma unroll
    for (int s = 0; s < 2; ++s)
        by[n][s] = *(const short8*)(E0 + (n * 16 + m) * 72 + s * 32 + q * 8);

    float* ob = out + (size_t)b * CCH * HWN;
#pragma unroll
    for (int mt = 0; mt < 4; ++mt) {
        f32x4 c[4];
#pragma unroll
        for (int n = 0; n < 4; ++n) c[n] = (f32x4){0.f,0.f,0.f,0.f};
#pragma unroll
        for (int s = 0; s < 2; ++s) {
            short8 aw = *(const short8*)(wzA + (((mt * 2 + s) * 64 + lane) << 3));
#pragma unroll
            for (int n = 0; n < 4; ++n)
                c[n] = __builtin_amdgcn_mfma_f32_16x16x32_bf16(aw, by[n][s], c[n], 0, 0, 0);
        }
        f32x4 wb = *(const f32x4*)(wzb + mt * 16 + q * 4);
#pragma unroll
        for (int r = 0; r < 4; ++r) {
            int o = mt * 16 + q * 4 + r;
            size_t base = (size_t)o * HWN + hw0 + m;
#pragma unroll
            for (int n = 0; n < 4; ++n)
                ob[base + n * 16] = c[n][r] * linv[n] + wb[r] + xb[base + n * 16];
        }
    }
}

extern "C" void kernel_launch(void* const* d_in, const int* in_sizes, int n_in,
                              void* d_out, int out_size, void* d_ws, size_t ws_size,
                              hipStream_t stream) {
    const float* x    = (const float*)d_in[0];
    const float* mb   = (const float*)d_in[1];
    const float* phiw = (const float*)d_in[2];
    const float* phib = (const float*)d_in[3];
    const float* gnw  = (const float*)d_in[4];
    const float* gnb  = (const float*)d_in[5];
    const float* wzw  = (const float*)d_in[6];
    const float* wzb  = (const float*)d_in[7];

    const int B = in_sizes[0] / (CCH * HWN);  // 10
    const int nstat = B * 128;                // 4 partial blocks per (b,g)

    // zero the atomic-sum region (float idx 36864..37504 of ws)
    hipMemsetAsync((char*)d_ws + 36864 * 4, 0, 640 * 4, stream);
    prep_stats_kernel<<<nstat + 288, 256, 0, stream>>>(x, mb, phiw, wzw,
                                                       (ushort*)d_ws, nstat);
    main_mfma<<<B * 128, 128, 0, stream>>>(x, (const ushort*)d_ws,
                                           phib, gnw, gnb, wzb, (float*)d_out);
}

// Round 8
// 180.412 us; speedup vs baseline: 1.3515x; 1.3515x over previous
//
#include <hip/hip_runtime.h>

// GroupNorm(32) -> phi 1x1 -> soft-VQ softmax vs codebook -> wz 1x1 + residual. fp32 I/O.
// x:(10,64,128,128), mb:(64,512), phi_w/wz_w:(64,64). B=10, C=64, HW=16384, K=512.
//
// One wave = 64 tokens (4 MFMA N-groups sharing all A-frag loads).
// All stages transposed (M=feature, N=token): C col = lane&15 = token everywhere.
// Per-wave LDS: ONE 64x72-ushort buffer (stride 72 dwords%32==4: b64 writes/b128
// reads are bank-floor-optimal; measured SQ_LDS_BANK_CONFLICT == structural width
// cost exactly). No __syncthreads in main: all LDS deps are intra-wave.
// __launch_bounds__(128,2): measured (128,4) caps VGPR at 64 -> catastrophic spill
// (274/347 MB scratch traffic, R7); (128,2) gives VGPR=128 = the 4-waves/SIMD
// boundary, and with 18.4 KB LDS the limiter is now VGPR not LDS.
//
// ws (ushort):
//  [0    ..32768) mbA  scores A-frags  (((cc*4+u)*2+s)*64+lane)*8+j = mb[s*32+q*8+j][(cc*4+u)*16+m]
//  [32768..65536) mbY  Y A-frags       (((cc*2+s2)*4+mt)*64+lane)*8+j = mb[mt*16+m][cc*64+s2*32+q*8+j]
//  [65536..69632) phiA ((mt*2+s)*64+lane)*8+j = phi_w[mt*16+m][s*32+q*8+j]
//  [69632..73728) wzA  same for wz_w
//  float view at ushort 73728: [0..320) mu[b*32+g], [320..640) rstd[b*32+g]

#define HWN 16384
#define CCH 64
#define PSC 0.18033688011112042f   // 0.125 * log2(e)

using short8 = __attribute__((ext_vector_type(8))) short;
using f32x4  = __attribute__((ext_vector_type(4))) float;

__device__ __forceinline__ ushort f2bf(float f) {
    union { float f; unsigned int i; } v; v.f = f;
    return (ushort)((v.i + 0x8000u) >> 16);   // round-half-up
}
__device__ __forceinline__ unsigned int pk2(float a, float b) {
    union { float f; unsigned int i; } va, vb; va.f = a; vb.f = b;
    return __builtin_amdgcn_perm(vb.i + 0x8000u, va.i + 0x8000u, 0x07060302u);
}

// blocks [0, nstat): GroupNorm stats (one block per (b,g)). [nstat, nstat+288): weight prep.
__global__ __launch_bounds__(256) void prep_stats_kernel(
    const float* __restrict__ x, const float* __restrict__ mb,
    const float* __restrict__ phiw, const float* __restrict__ wzw,
    ushort* __restrict__ ws, int nstat)
{
    if (blockIdx.x >= nstat) {
        int i = (blockIdx.x - nstat) * 256 + threadIdx.x;   // 0..73727
        int j = i & 7, lane = (i >> 3) & 63, m = lane & 15, q = lane >> 4;
        if (i < 32768) {
            int t = i >> 9, tile = t >> 1, s = t & 1;
            ws[i] = f2bf(mb[(s * 32 + q * 8 + j) * 512 + tile * 16 + m]);
        } else if (i < 65536) {
            int t = (i - 32768) >> 9;
            int mt = t & 3, u2 = t >> 2, s2 = u2 & 1, cc = u2 >> 1;
            ws[i] = f2bf(mb[(mt * 16 + m) * 512 + cc * 64 + s2 * 32 + q * 8 + j]);
        } else if (i < 69632) {
            int t = (i - 65536) >> 9, mt = t >> 1, s = t & 1;
            ws[i] = f2bf(phiw[(mt * 16 + m) * 64 + s * 32 + q * 8 + j]);
        } else {
            int t = (i - 69632) >> 9, mt = t >> 1, s = t & 1;
            ws[i] = f2bf(wzw[(mt * 16 + m) * 64 + s * 32 + q * 8 + j]);
        }
        return;
    }
    float* wsf = (float*)(ws + 73728);
    int b = blockIdx.x >> 5;
    int g = blockIdx.x & 31;
    const float4* b4 = (const float4*)(x + (size_t)b * CCH * HWN + (size_t)(g * 2) * HWN);
    float s = 0.f, s2 = 0.f;
    for (int i = threadIdx.x; i < 8192; i += 256) {
        float4 u = b4[i];
        s  += (u.x + u.y) + (u.z + u.w);
        s2 += (u.x*u.x + u.y*u.y) + (u.z*u.z + u.w*u.w);
    }
    for (int off = 32; off > 0; off >>= 1) {
        s  += __shfl_down(s, off);
        s2 += __shfl_down(s2, off);
    }
    __shared__ float rs[4], rs2[4];
    int wave = threadIdx.x >> 6, lane = threadIdx.x & 63;
    if (lane == 0) { rs[wave] = s; rs2[wave] = s2; }
    __syncthreads();
    if (threadIdx.x == 0) {
        float ts  = rs[0] + rs[1] + rs[2] + rs[3];
        float ts2 = rs2[0] + rs2[1] + rs2[2] + rs2[3];
        float mu  = ts * (1.f / 32768.f);
        float var = ts2 * (1.f / 32768.f) - mu * mu;
        wsf[b * 32 + g]       = mu;
        wsf[320 + b * 32 + g] = rsqrtf(var + 1e-6f);
    }
}

__global__ __launch_bounds__(128, 2) void main_mfma(
    const float* __restrict__ x, const ushort* __restrict__ ws,
    const float* __restrict__ phib, const float* __restrict__ gnw,
    const float* __restrict__ gnb, const float* __restrict__ wzb,
    float* __restrict__ out)
{
    const int lane = threadIdx.x & 63, wv = threadIdx.x >> 6;
    const int m = lane & 15, q = lane >> 4;
    const int blk = blockIdx.x;                       // 1280 blocks, 128 tokens each
    const int b   = blk >> 7;                         // 128 blocks per image
    const int hw0 = ((blk & 127) << 7) + (wv << 6);   // this wave's 64 tokens

    const ushort* mbA  = ws;
    const ushort* mbY  = ws + 32768;
    const ushort* phiA = ws + 65536;
    const ushort* wzA  = ws + 69632;
    const float*  statf = (const float*)(ws + 73728);

    __shared__ ushort Sl[2][64 * 72];                 // one buffer per wave
    ushort* E0 = &Sl[wv][0];

    const float* xb = x + (size_t)b * CCH * HWN;

    // ---- stage 1: x -> GroupNorm -> bf16 B-frags (4 token groups) ----
    short8 bx[4][2];
#pragma unroll
    for (int s = 0; s < 2; ++s) {
        const int cbase = s * 32 + q * 8;
        f32x4 mu4 = *(const f32x4*)(statf + b * 32 + (cbase >> 1));
        f32x4 rs4 = *(const f32x4*)(statf + 320 + b * 32 + (cbase >> 1));
        f32x4 gwv0 = *(const f32x4*)(gnw + cbase), gwv1 = *(const f32x4*)(gnw + cbase + 4);
        f32x4 gbv0 = *(const f32x4*)(gnb + cbase), gbv1 = *(const f32x4*)(gnb + cbase + 4);
#pragma unroll
        for (int n = 0; n < 4; ++n)
#pragma unroll
        for (int j = 0; j < 8; ++j) {
            float v  = xb[(size_t)(cbase + j) * HWN + hw0 + n * 16 + m];
            float gw = (j < 4) ? gwv0[j & 3] : gwv1[j & 3];
            float gb = (j < 4) ? gbv0[j & 3] : gbv1[j & 3];
            float xn = (v - mu4[j >> 1]) * rs4[j >> 1] * gw + gb;
            bx[n][s][j] = (short)f2bf(xn);
        }
    }

    // ---- P^T = phi_w * xn ; store scaled by PSC so softmax exp is bare exp2 ----
#pragma unroll
    for (int mt = 0; mt < 4; ++mt) {
        f32x4 a[4];
#pragma unroll
        for (int n = 0; n < 4; ++n) a[n] = (f32x4){0.f,0.f,0.f,0.f};
#pragma unroll
        for (int s = 0; s < 2; ++s) {
            short8 ap = *(const short8*)(phiA + (((mt * 2 + s) * 64 + lane) << 3));
#pragma unroll
            for (int n = 0; n < 4; ++n)
                a[n] = __builtin_amdgcn_mfma_f32_16x16x32_bf16(ap, bx[n][s], a[n], 0, 0, 0);
        }
        f32x4 pb = *(const f32x4*)(phib + mt * 16 + q * 4);
#pragma unroll
        for (int n = 0; n < 4; ++n)
            *(uint2*)(E0 + (n * 16 + m) * 72 + mt * 16 + q * 4) =
                make_uint2(pk2((a[n][0]+pb[0])*PSC, (a[n][1]+pb[1])*PSC),
                           pk2((a[n][2]+pb[2])*PSC, (a[n][3]+pb[3])*PSC));
    }

    // hoist this lane's token-rows of P (chunk-invariant score B-frags)
    short8 bp[4][2];
#pragma unroll
    for (int n = 0; n < 4; ++n)
#pragma unroll
    for (int s = 0; s < 2; ++s)
        bp[n][s] = *(const short8*)(E0 + (n * 16 + m) * 72 + s * 32 + q * 8);

    // ---- streaming softmax + Y over 8 chunks of 64 codebook entries ----
    f32x4 accY[4][4];
#pragma unroll
    for (int n = 0; n < 4; ++n)
#pragma unroll
    for (int mt = 0; mt < 4; ++mt) accY[n][mt] = (f32x4){0.f,0.f,0.f,0.f};
    float lsum[4] = {0.f, 0.f, 0.f, 0.f};

    for (int cc = 0; cc < 8; ++cc) {
#pragma unroll
        for (int u = 0; u < 4; ++u) {
            short8 am0 = *(const short8*)(mbA + ((((cc * 4 + u) * 2 + 0) * 64 + lane) << 3));
            short8 am1 = *(const short8*)(mbA + ((((cc * 4 + u) * 2 + 1) * 64 + lane) << 3));
#pragma unroll
            for (int n = 0; n < 4; ++n) {
                f32x4 sa = {0.f,0.f,0.f,0.f};
                sa = __builtin_amdgcn_mfma_f32_16x16x32_bf16(am0, bp[n][0], sa, 0, 0, 0);
                sa = __builtin_amdgcn_mfma_f32_16x16x32_bf16(am1, bp[n][1], sa, 0, 0, 0);
                float e0 = __builtin_exp2f(sa[0]), e1 = __builtin_exp2f(sa[1]);
                float e2 = __builtin_exp2f(sa[2]), e3 = __builtin_exp2f(sa[3]);
                lsum[n] += (e0 + e1) + (e2 + e3);
                *(uint2*)(E0 + (n * 16 + m) * 72 + u * 16 + q * 4) =
                    make_uint2(pk2(e0, e1), pk2(e2, e3));
            }
        }
#pragma unroll
        for (int s2 = 0; s2 < 2; ++s2) {
            short8 be[4];
#pragma unroll
            for (int n = 0; n < 4; ++n)
                be[n] = *(const short8*)(E0 + (n * 16 + m) * 72 + s2 * 32 + q * 8);
#pragma unroll
            for (int mt = 0; mt < 4; ++mt) {
                short8 ay = *(const short8*)(mbY + ((((cc * 2 + s2) * 4 + mt) * 64 + lane) << 3));
#pragma unroll
                for (int n = 0; n < 4; ++n)
                    accY[n][mt] = __builtin_amdgcn_mfma_f32_16x16x32_bf16(ay, be[n], accY[n][mt], 0, 0, 0);
            }
        }
    }

    // softmax denominators: lane's C-column IS its token; reduce across q
    float linv[4];
#pragma unroll
    for (int n = 0; n < 4; ++n) {
        float l = lsum[n];
        l += __shfl_xor(l, 16);
        l += __shfl_xor(l, 32);
        linv[n] = 1.f / l;
    }

    // ---- Y -> LDS (B-layout), then Out^T = wz * Y ----
#pragma unroll
    for (int mt = 0; mt < 4; ++mt)
#pragma unroll
    for (int n = 0; n < 4; ++n)
        *(uint2*)(E0 + (n * 16 + m) * 72 + mt * 16 + q * 4) =
            make_uint2(pk2(accY[n][mt][0], accY[n][mt][1]), pk2(accY[n][mt][2], accY[n][mt][3]));

    short8 by[4][2];
#pragma unroll
    for (int n = 0; n < 4; ++n)
#pragma unroll
    for (int s = 0; s < 2; ++s)
        by[n][s] = *(const short8*)(E0 + (n * 16 + m) * 72 + s * 32 + q * 8);

    float* ob = out + (size_t)b * CCH * HWN;
#pragma unroll
    for (int mt = 0; mt < 4; ++mt) {
        f32x4 c[4];
#pragma unroll
        for (int n = 0; n < 4; ++n) c[n] = (f32x4){0.f,0.f,0.f,0.f};
#pragma unroll
        for (int s = 0; s < 2; ++s) {
            short8 aw = *(const short8*)(wzA + (((mt * 2 + s) * 64 + lane) << 3));
#pragma unroll
            for (int n = 0; n < 4; ++n)
                c[n] = __builtin_amdgcn_mfma_f32_16x16x32_bf16(aw, by[n][s], c[n], 0, 0, 0);
        }
        f32x4 wb = *(const f32x4*)(wzb + mt * 16 + q * 4);
#pragma unroll
        for (int r = 0; r < 4; ++r) {
            int o = mt * 16 + q * 4 + r;
            size_t base = (size_t)o * HWN + hw0 + m;
#pragma unroll
            for (int n = 0; n < 4; ++n)
                ob[base + n * 16] = c[n][r] * linv[n] + wb[r] + xb[base + n * 16];
        }
    }
}

extern "C" void kernel_launch(void* const* d_in, const int* in_sizes, int n_in,
                              void* d_out, int out_size, void* d_ws, size_t ws_size,
                              hipStream_t stream) {
    const float* x    = (const float*)d_in[0];
    const float* mb   = (const float*)d_in[1];
    const float* phiw = (const float*)d_in[2];
    const float* phib = (const float*)d_in[3];
    const float* gnw  = (const float*)d_in[4];
    const float* gnb  = (const float*)d_in[5];
    const float* wzw  = (const float*)d_in[6];
    const float* wzb  = (const float*)d_in[7];

    const int B = in_sizes[0] / (CCH * HWN);  // 10

    prep_stats_kernel<<<B * 32 + 288, 256, 0, stream>>>(x, mb, phiw, wzw,
                                                        (ushort*)d_ws, B * 32);
    main_mfma<<<B * 128, 128, 0, stream>>>(x, (const ushort*)d_ws,
                                           phib, gnw, gnb, wzb, (float*)d_out);
}

// Round 9
// 175.298 us; speedup vs baseline: 1.3909x; 1.0292x over previous
//
#include <hip/hip_runtime.h>

// GroupNorm(32) -> phi 1x1 -> soft-VQ softmax vs codebook -> wz 1x1 + residual. fp32 I/O.
// x:(10,64,128,128), mb:(64,512), phi_w/wz_w:(64,64). B=10, C=64, HW=16384, K=512.
//
// R9 synthesis of measured results:
//  - 32 tokens/wave, 128-thr blocks: 5120 waves (R5 showed parallelism wins; R6/R8's
//    64-token waves starved the SIMDs at 2560 waves).
//  - Double-buffered exp LDS (R6>R8 showed single buffer serializes chunks via WAR).
//  - exp2/PSC + v_perm bf16 pack (VALU diet, R8).
//  - __launch_bounds__(128,2): (128,4) forces VGPR=64 -> catastrophic spill (R7).
//  - Stride-72 rows, no swizzle: SQ_LDS_BANK_CONFLICT == structural width cost only.
//  - 8-way-split atomic GroupNorm stats (R7 scheme; sums finalized in main prologue).
//
// ws (ushort):
//  [0    ..32768) mbA  scores A-frags  (((cc*4+u)*2+s)*64+lane)*8+j = mb[s*32+q*8+j][(cc*4+u)*16+m]
//  [32768..65536) mbY  Y A-frags       (((cc*2+s2)*4+mt)*64+lane)*8+j = mb[mt*16+m][cc*64+s2*32+q*8+j]
//  [65536..69632) phiA ((mt*2+s)*64+lane)*8+j = phi_w[mt*16+m][s*32+q*8+j]
//  [69632..73728) wzA  same for wz_w
//  float view at ushort 73728 (statf): [0..320) sum[b*32+g], [320..640) sumsq (atomic)

#define HWN 16384
#define CCH 64
#define PSC 0.18033688011112042f   // 0.125 * log2(e)

using short8 = __attribute__((ext_vector_type(8))) short;
using f32x4  = __attribute__((ext_vector_type(4))) float;

__device__ __forceinline__ ushort f2bf(float f) {
    union { float f; unsigned int i; } v; v.f = f;
    return (ushort)((v.i + 0x8000u) >> 16);   // round-half-up
}
__device__ __forceinline__ unsigned int pk2(float a, float b) {
    union { float f; unsigned int i; } va, vb; va.f = a; vb.f = b;
    return __builtin_amdgcn_perm(vb.i + 0x8000u, va.i + 0x8000u, 0x07060302u);
}

// blocks [0, nstat): GroupNorm partial sums, 8 parts per (b,g), atomicAdd into statf.
// blocks [nstat, nstat+288): weight prep gathers.
__global__ __launch_bounds__(256) void prep_stats_kernel(
    const float* __restrict__ x, const float* __restrict__ mb,
    const float* __restrict__ phiw, const float* __restrict__ wzw,
    ushort* __restrict__ ws, int nstat)
{
    if (blockIdx.x >= nstat) {
        int i = (blockIdx.x - nstat) * 256 + threadIdx.x;   // 0..73727
        int j = i & 7, lane = (i >> 3) & 63, m = lane & 15, q = lane >> 4;
        if (i < 32768) {
            int t = i >> 9, tile = t >> 1, s = t & 1;
            ws[i] = f2bf(mb[(s * 32 + q * 8 + j) * 512 + tile * 16 + m]);
        } else if (i < 65536) {
            int t = (i - 32768) >> 9;
            int mt = t & 3, u2 = t >> 2, s2 = u2 & 1, cc = u2 >> 1;
            ws[i] = f2bf(mb[(mt * 16 + m) * 512 + cc * 64 + s2 * 32 + q * 8 + j]);
        } else if (i < 69632) {
            int t = (i - 65536) >> 9, mt = t >> 1, s = t & 1;
            ws[i] = f2bf(phiw[(mt * 16 + m) * 64 + s * 32 + q * 8 + j]);
        } else {
            int t = (i - 69632) >> 9, mt = t >> 1, s = t & 1;
            ws[i] = f2bf(wzw[(mt * 16 + m) * 64 + s * 32 + q * 8 + j]);
        }
        return;
    }
    float* statf = (float*)(ws + 73728);
    int blk  = blockIdx.x;            // b*256 + g*8 + part
    int b    = blk >> 8;
    int g    = (blk >> 3) & 31;
    int part = blk & 7;
    const float4* b4 = (const float4*)(x + (size_t)b * CCH * HWN + (size_t)(g * 2) * HWN) + part * 1024;
    float s = 0.f, s2 = 0.f;
    for (int i = threadIdx.x; i < 1024; i += 256) {
        float4 u = b4[i];
        s  += (u.x + u.y) + (u.z + u.w);
        s2 += (u.x*u.x + u.y*u.y) + (u.z*u.z + u.w*u.w);
    }
    for (int off = 32; off > 0; off >>= 1) {
        s  += __shfl_down(s, off);
        s2 += __shfl_down(s2, off);
    }
    __shared__ float rs[4], rs2[4];
    int wave = threadIdx.x >> 6, lane = threadIdx.x & 63;
    if (lane == 0) { rs[wave] = s; rs2[wave] = s2; }
    __syncthreads();
    if (threadIdx.x == 0) {
        atomicAdd(&statf[b * 32 + g],       rs[0] + rs[1] + rs[2] + rs[3]);
        atomicAdd(&statf[320 + b * 32 + g], rs2[0] + rs2[1] + rs2[2] + rs2[3]);
    }
}

__global__ __launch_bounds__(128, 2) void main_mfma(
    const float* __restrict__ x, const ushort* __restrict__ ws,
    const float* __restrict__ phib, const float* __restrict__ gnw,
    const float* __restrict__ gnb, const float* __restrict__ wzb,
    float* __restrict__ out)
{
    const int lane = threadIdx.x & 63, wv = threadIdx.x >> 6;
    const int m = lane & 15, q = lane >> 4;
    const int blk = blockIdx.x;                       // 2560 blocks, 64 tokens each
    const int b   = blk >> 8;                         // 256 blocks per image
    const int hw0 = ((blk & 255) << 6) + (wv << 5);   // this wave's 32 tokens

    const ushort* mbA  = ws;
    const ushort* mbY  = ws + 32768;
    const ushort* phiA = ws + 65536;
    const ushort* wzA  = ws + 69632;
    const float*  statf = (const float*)(ws + 73728);

    __shared__ ushort Sl[2][2][32 * 72];              // [wave][parity]
    ushort* Ebuf[2] = { &Sl[wv][0][0], &Sl[wv][1][0] };
    ushort* E0 = Ebuf[0];

    const float* xb = x + (size_t)b * CCH * HWN;

    // ---- stage 1: x -> GroupNorm (finalize from atomic sums) -> bf16 B-frags ----
    short8 bx[2][2];
#pragma unroll
    for (int s = 0; s < 2; ++s) {
        const int cbase = s * 32 + q * 8;
        f32x4 sm4 = *(const f32x4*)(statf + b * 32 + (cbase >> 1));
        f32x4 sq4 = *(const f32x4*)(statf + 320 + b * 32 + (cbase >> 1));
        f32x4 mu4, rs4;
#pragma unroll
        for (int r = 0; r < 4; ++r) {
            mu4[r] = sm4[r] * (1.f / 32768.f);
            float var = sq4[r] * (1.f / 32768.f) - mu4[r] * mu4[r];
            rs4[r] = rsqrtf(var + 1e-6f);
        }
        f32x4 gwv0 = *(const f32x4*)(gnw + cbase), gwv1 = *(const f32x4*)(gnw + cbase + 4);
        f32x4 gbv0 = *(const f32x4*)(gnb + cbase), gbv1 = *(const f32x4*)(gnb + cbase + 4);
#pragma unroll
        for (int n = 0; n < 2; ++n)
#pragma unroll
        for (int j = 0; j < 8; ++j) {
            float v  = xb[(size_t)(cbase + j) * HWN + hw0 + n * 16 + m];
            float gw = (j < 4) ? gwv0[j & 3] : gwv1[j & 3];
            float gb = (j < 4) ? gbv0[j & 3] : gbv1[j & 3];
            float xn = (v - mu4[j >> 1]) * rs4[j >> 1] * gw + gb;
            bx[n][s][j] = (short)f2bf(xn);
        }
    }

    // ---- P^T = phi_w * xn ; store scaled by PSC so softmax exp is bare exp2 ----
#pragma unroll
    for (int mt = 0; mt < 4; ++mt) {
        f32x4 a[2];
#pragma unroll
        for (int n = 0; n < 2; ++n) a[n] = (f32x4){0.f,0.f,0.f,0.f};
#pragma unroll
        for (int s = 0; s < 2; ++s) {
            short8 ap = *(const short8*)(phiA + (((mt * 2 + s) * 64 + lane) << 3));
#pragma unroll
            for (int n = 0; n < 2; ++n)
                a[n] = __builtin_amdgcn_mfma_f32_16x16x32_bf16(ap, bx[n][s], a[n], 0, 0, 0);
        }
        f32x4 pb = *(const f32x4*)(phib + mt * 16 + q * 4);
#pragma unroll
        for (int n = 0; n < 2; ++n)
            *(uint2*)(E0 + (n * 16 + m) * 72 + mt * 16 + q * 4) =
                make_uint2(pk2((a[n][0]+pb[0])*PSC, (a[n][1]+pb[1])*PSC),
                           pk2((a[n][2]+pb[2])*PSC, (a[n][3]+pb[3])*PSC));
    }

    // hoist this lane's token-rows of P (chunk-invariant score B-frags)
    short8 bp[2][2];
#pragma unroll
    for (int n = 0; n < 2; ++n)
#pragma unroll
    for (int s = 0; s < 2; ++s)
        bp[n][s] = *(const short8*)(E0 + (n * 16 + m) * 72 + s * 32 + q * 8);

    // ---- streaming softmax + Y over 8 chunks of 64 codebook entries ----
    f32x4 accY[2][4];
#pragma unroll
    for (int n = 0; n < 2; ++n)
#pragma unroll
    for (int mt = 0; mt < 4; ++mt) accY[n][mt] = (f32x4){0.f,0.f,0.f,0.f};
    float lsum[2] = {0.f, 0.f};

    for (int cc = 0; cc < 8; ++cc) {
        ushort* Eb = Ebuf[cc & 1];
#pragma unroll
        for (int u = 0; u < 4; ++u) {
            short8 am0 = *(const short8*)(mbA + ((((cc * 4 + u) * 2 + 0) * 64 + lane) << 3));
            short8 am1 = *(const short8*)(mbA + ((((cc * 4 + u) * 2 + 1) * 64 + lane) << 3));
#pragma unroll
            for (int n = 0; n < 2; ++n) {
                f32x4 sa = {0.f,0.f,0.f,0.f};
                sa = __builtin_amdgcn_mfma_f32_16x16x32_bf16(am0, bp[n][0], sa, 0, 0, 0);
                sa = __builtin_amdgcn_mfma_f32_16x16x32_bf16(am1, bp[n][1], sa, 0, 0, 0);
                float e0 = __builtin_exp2f(sa[0]), e1 = __builtin_exp2f(sa[1]);
                float e2 = __builtin_exp2f(sa[2]), e3 = __builtin_exp2f(sa[3]);
                lsum[n] += (e0 + e1) + (e2 + e3);
                *(uint2*)(Eb + (n * 16 + m) * 72 + u * 16 + q * 4) =
                    make_uint2(pk2(e0, e1), pk2(e2, e3));
            }
        }
#pragma unroll
        for (int s2 = 0; s2 < 2; ++s2) {
            short8 be[2];
#pragma unroll
            for (int n = 0; n < 2; ++n)
                be[n] = *(const short8*)(Eb + (n * 16 + m) * 72 + s2 * 32 + q * 8);
#pragma unroll
            for (int mt = 0; mt < 4; ++mt) {
                short8 ay = *(const short8*)(mbY + ((((cc * 2 + s2) * 4 + mt) * 64 + lane) << 3));
#pragma unroll
                for (int n = 0; n < 2; ++n)
                    accY[n][mt] = __builtin_amdgcn_mfma_f32_16x16x32_bf16(ay, be[n], accY[n][mt], 0, 0, 0);
            }
        }
    }

    // softmax denominators: lane's C-column IS its token; reduce across q
    float linv[2];
#pragma unroll
    for (int n = 0; n < 2; ++n) {
        float l = lsum[n];
        l += __shfl_xor(l, 16);
        l += __shfl_xor(l, 32);
        linv[n] = 1.f / l;
    }

    // ---- Y -> LDS (B-layout), then Out^T = wz * Y ----
#pragma unroll
    for (int mt = 0; mt < 4; ++mt)
#pragma unroll
    for (int n = 0; n < 2; ++n)
        *(uint2*)(E0 + (n * 16 + m) * 72 + mt * 16 + q * 4) =
            make_uint2(pk2(accY[n][mt][0], accY[n][mt][1]), pk2(accY[n][mt][2], accY[n][mt][3]));

    short8 by[2][2];
#pragma unroll
    for (int n = 0; n < 2; ++n)
#pragma unroll
    for (int s = 0; s < 2; ++s)
        by[n][s] = *(const short8*)(E0 + (n * 16 + m) * 72 + s * 32 + q * 8);

    float* ob = out + (size_t)b * CCH * HWN;
#pragma unroll
    for (int mt = 0; mt < 4; ++mt) {
        f32x4 c[2];
#pragma unroll
        for (int n = 0; n < 2; ++n) c[n] = (f32x4){0.f,0.f,0.f,0.f};
#pragma unroll
        for (int s = 0; s < 2; ++s) {
            short8 aw = *(const short8*)(wzA + (((mt * 2 + s) * 64 + lane) << 3));
#pragma unroll
            for (int n = 0; n < 2; ++n)
                c[n] = __builtin_amdgcn_mfma_f32_16x16x32_bf16(aw, by[n][s], c[n], 0, 0, 0);
        }
        f32x4 wb = *(const f32x4*)(wzb + mt * 16 + q * 4);
#pragma unroll
        for (int r = 0; r < 4; ++r) {
            int o = mt * 16 + q * 4 + r;
            size_t base = (size_t)o * HWN + hw0 + m;
#pragma unroll
            for (int n = 0; n < 2; ++n)
                ob[base + n * 16] = c[n][r] * linv[n] + wb[r] + xb[base + n * 16];
        }
    }
}

extern "C" void kernel_launch(void* const* d_in, const int* in_sizes, int n_in,
                              void* d_out, int out_size, void* d_ws, size_t ws_size,
                              hipStream_t stream) {
    const float* x    = (const float*)d_in[0];
    const float* mb   = (const float*)d_in[1];
    const float* phiw = (const float*)d_in[2];
    const float* phib = (const float*)d_in[3];
    const float* gnw  = (const float*)d_in[4];
    const float* gnb  = (const float*)d_in[5];
    const float* wzw  = (const float*)d_in[6];
    const float* wzb  = (const float*)d_in[7];

    const int B = in_sizes[0] / (CCH * HWN);  // 10
    const int nstat = B * 256;                // 8 partial blocks per (b,g)

    // zero the atomic-sum region (float idx 36864..37504 of ws)
    hipMemsetAsync((char*)d_ws + 36864 * 4, 0, 640 * 4, stream);
    prep_stats_kernel<<<nstat + 288, 256, 0, stream>>>(x, mb, phiw, wzw,
                                                       (ushort*)d_ws, nstat);
    main_mfma<<<B * 256, 128, 0, stream>>>(x, (const ushort*)d_ws,
                                           phib, gnw, gnb, wzb, (float*)d_out);
}